// Round 2
// baseline (2843.297 us; speedup 1.0000x reference)
//
#include <hip/hip_runtime.h>

#define NBLK 1024
#define NTHR 256

#define PNB 256
#define PNT 512
#define PRPT 16   // pairs/thread in persistent fallback: 256*512*16 = 2,097,152 pairs

__device__ __forceinline__ float ex2(float x) { return __builtin_amdgcn_exp2f(x); }

__device__ __forceinline__ float rcp_acc(float d) {
  float r = __builtin_amdgcn_rcpf(d);
  return r * __builtin_fmaf(-d, r, 2.0f);          // 1 NR step
}
__device__ __forceinline__ float div_acc(float n, float d, float r) {
  float q = n * r;
  float rho = __builtin_fmaf(-q, d, n);            // residual
  return __builtin_fmaf(rho, r, q);                // corrected quotient
}

// BN+tanh+affine for one element. P,Q fold BN and the 2*log2(e) tanh prescale (f64).
__device__ __forceinline__ float actf(float y, double P, double Q, float sc, float sh) {
  double u = fma((double)y, P, Q);
  float uf = (float)u;
  uf = fminf(fmaxf(uf, -60.0f), 60.0f);
  float e = ex2(uf);
  float den = e + 1.0f;
  float r = rcp_acc(den);
  float t = div_acc(e - 1.0f, den, r);             // tanh
  return __builtin_fmaf(t, sc, sh);
}

__device__ __forceinline__ float sigm(double uo) {
  const double C1 = 1.4426950408889634074;         // log2(e)
  float w = (float)(-uo * C1);
  w = fminf(fmaxf(w, -60.0f), 60.0f);
  float e = ex2(w);
  float d = 1.0f + e;
  float r = rcp_acc(d);
  return div_acc(1.0f, d, r);
}

// block-level 4-way f64 reduction -> one atomicAdd per stat per block
__device__ __forceinline__ void red4(double* dst, double s0, double s1, double s2, double s3) {
  __shared__ double lr[8][4];
  const int lane = threadIdx.x & 63, wave = threadIdx.x >> 6;
#pragma unroll
  for (int off = 32; off > 0; off >>= 1) {
    s0 += __shfl_down(s0, off, 64);
    s1 += __shfl_down(s1, off, 64);
    s2 += __shfl_down(s2, off, 64);
    s3 += __shfl_down(s3, off, 64);
  }
  if (lane == 0) { lr[wave][0] = s0; lr[wave][1] = s1; lr[wave][2] = s2; lr[wave][3] = s3; }
  __syncthreads();
  if (threadIdx.x == 0) {
    const int nw = blockDim.x >> 6;
    double a0 = 0, a1 = 0, a2 = 0, a3 = 0;
    for (int w = 0; w < nw; ++w) { a0 += lr[w][0]; a1 += lr[w][1]; a2 += lr[w][2]; a3 += lr[w][3]; }
    atomicAdd(dst + 0, a0); atomicAdd(dst + 1, a1);
    atomicAdd(dst + 2, a2); atomicAdd(dst + 3, a3);
  }
  __syncthreads();
}

// ---------------- multi-launch path: one kernel per layer ----------------
// MODE 0: x -> y0 (+stats0).  MODE 1: y_l -> y_{l+1} (+stats_{l+1}).  MODE 2: y_{L-1} -> out.
template <int MODE>
__global__ __launch_bounds__(NTHR) void layer_k(
    const float4* __restrict__ in, float4* __restrict__ yout, float2* __restrict__ ofin,
    const float* __restrict__ Wl, const float* __restrict__ bl,
    const float* __restrict__ gl, const float* __restrict__ bel,
    const float* __restrict__ scl, const float* __restrict__ shl,
    const double* __restrict__ accin, double* __restrict__ accout, int N2)
{
  double P0 = 0, Q0 = 0, P1 = 0, Q1 = 0;
  float sc0 = 0, sh0 = 0, sc1 = 0, sh1 = 0;
  if (MODE >= 1) {
    const double dn = 0.5 / (double)N2;            // 1/N
    const double m0 = accin[0] * dn, m1 = accin[1] * dn;
    const double v0 = fma(-m0, m0, accin[2] * dn);
    const double v1 = fma(-m1, m1, accin[3] * dn);
    const double rs0 = 1.0 / sqrt(v0 + 1e-5);
    const double rs1 = 1.0 / sqrt(v1 + 1e-5);
    const double A0 = (double)gl[0] * rs0, A1 = (double)gl[1] * rs1;
    const double C2 = 2.8853900817779268147;       // 2*log2(e)
    P0 = A0 * C2; P1 = A1 * C2;
    Q0 = ((double)bel[0] - m0 * A0) * C2;
    Q1 = ((double)bel[1] - m1 * A1) * C2;
    sc0 = scl[0]; sh0 = shl[0]; sc1 = scl[1]; sh1 = shl[1];
  }
  double w00 = 0, w01 = 0, w10 = 0, w11 = 0, b0 = 0, b1 = 0;
  if (MODE <= 1) {
    w00 = Wl[0]; w01 = Wl[1]; w10 = Wl[2]; w11 = Wl[3]; b0 = bl[0]; b1 = bl[1];
  } else {
    w00 = Wl[0]; w01 = Wl[1]; b0 = bl[0];
  }

  double s0 = 0, s1 = 0, s2 = 0, s3 = 0;
  for (int i = blockIdx.x * blockDim.x + threadIdx.x; i < N2; i += gridDim.x * blockDim.x) {
    const float4 p = in[i];
    float z0, z1, z2, z3;
    if (MODE == 0) { z0 = p.x; z1 = p.y; z2 = p.z; z3 = p.w; }
    else {
      z0 = actf(p.x, P0, Q0, sc0, sh0);
      z1 = actf(p.y, P1, Q1, sc1, sh1);
      z2 = actf(p.z, P0, Q0, sc0, sh0);
      z3 = actf(p.w, P1, Q1, sc1, sh1);
    }
    if (MODE <= 1) {
      const double a0 = fma((double)z0, w00, fma((double)z1, w01, b0));
      const double a1 = fma((double)z0, w10, fma((double)z1, w11, b1));
      const double a2 = fma((double)z2, w00, fma((double)z3, w01, b0));
      const double a3 = fma((double)z2, w10, fma((double)z3, w11, b1));
      yout[i] = make_float4((float)a0, (float)a1, (float)a2, (float)a3);
      s0 += a0 + a2; s1 += a1 + a3;
      s2 = fma(a0, a0, fma(a2, a2, s2));
      s3 = fma(a1, a1, fma(a3, a3, s3));
    } else {
      const double u0 = fma((double)z0, w00, fma((double)z1, w01, b0));
      const double u1 = fma((double)z2, w00, fma((double)z3, w01, b0));
      ofin[i] = make_float2(sigm(u0), sigm(u1));
    }
  }
  if (MODE <= 1) red4(accout, s0, s1, s2, s3);
}

// ---------------- persistent fallback (only if ws too small) ----------------
__device__ __forceinline__ void gbar(unsigned* cnt, unsigned* gen, int nblk) {
  __syncthreads();
  if (threadIdx.x == 0) {
    unsigned g = __hip_atomic_load(gen, __ATOMIC_ACQUIRE, __HIP_MEMORY_SCOPE_AGENT);
    unsigned old = __hip_atomic_fetch_add(cnt, 1u, __ATOMIC_ACQ_REL, __HIP_MEMORY_SCOPE_AGENT);
    if (old == (unsigned)(nblk - 1)) {
      __hip_atomic_store(cnt, 0u, __ATOMIC_RELAXED, __HIP_MEMORY_SCOPE_AGENT);
      __hip_atomic_store(gen, g + 1u, __ATOMIC_RELEASE, __HIP_MEMORY_SCOPE_AGENT);
    } else {
      while (__hip_atomic_load(gen, __ATOMIC_ACQUIRE, __HIP_MEMORY_SCOPE_AGENT) == g)
        __builtin_amdgcn_s_sleep(8);
    }
  }
  __syncthreads();
}

__global__ __launch_bounds__(PNT, 2) void fraud_persist(
    const float4* __restrict__ x, const float* __restrict__ W,
    const float* __restrict__ b, const float* __restrict__ gm,
    const float* __restrict__ bt, const float* __restrict__ sc,
    const float* __restrict__ sh, const float* __restrict__ Wf,
    const float* __restrict__ bf, float2* __restrict__ out,
    double* __restrict__ acc, unsigned* __restrict__ bar, int N2, int L)
{
  __shared__ double lb[4];
  const int tid = blockIdx.x * PNT + threadIdx.x;
  const int TT = PNB * PNT;
  float4 y[PRPT];
  double s0 = 0, s1 = 0, s2 = 0, s3 = 0;
  {
    const double w00 = W[0], w01 = W[1], w10 = W[2], w11 = W[3], b0 = b[0], b1 = b[1];
#pragma unroll
    for (int r = 0; r < PRPT; ++r) {
      const int i = tid + r * TT;
      const float4 p = (i < N2) ? x[i] : make_float4(0.f, 0.f, 0.f, 0.f);
      const double a0 = fma((double)p.x, w00, fma((double)p.y, w01, b0));
      const double a1 = fma((double)p.x, w10, fma((double)p.y, w11, b1));
      const double a2 = fma((double)p.z, w00, fma((double)p.w, w01, b0));
      const double a3 = fma((double)p.z, w10, fma((double)p.w, w11, b1));
      y[r] = make_float4((float)a0, (float)a1, (float)a2, (float)a3);
      if (i < N2) {
        s0 += a0 + a2; s1 += a1 + a3;
        s2 = fma(a0, a0, fma(a2, a2, s2));
        s3 = fma(a1, a1, fma(a3, a3, s3));
      }
    }
  }
  red4(acc, s0, s1, s2, s3);
  gbar(bar, bar + 1, PNB);

  const double dn = 0.5 / (double)N2;
  const double C2 = 2.8853900817779268147;
  for (int l = 0; l < L; ++l) {
    if (threadIdx.x == 0) {
      lb[0] = __hip_atomic_load(acc + 4 * l + 0, __ATOMIC_ACQUIRE, __HIP_MEMORY_SCOPE_AGENT);
      lb[1] = __hip_atomic_load(acc + 4 * l + 1, __ATOMIC_ACQUIRE, __HIP_MEMORY_SCOPE_AGENT);
      lb[2] = __hip_atomic_load(acc + 4 * l + 2, __ATOMIC_ACQUIRE, __HIP_MEMORY_SCOPE_AGENT);
      lb[3] = __hip_atomic_load(acc + 4 * l + 3, __ATOMIC_ACQUIRE, __HIP_MEMORY_SCOPE_AGENT);
    }
    __syncthreads();
    const double m0 = lb[0] * dn, m1 = lb[1] * dn;
    const double v0 = fma(-m0, m0, lb[2] * dn);
    const double v1 = fma(-m1, m1, lb[3] * dn);
    const double rs0 = 1.0 / sqrt(v0 + 1e-5);
    const double rs1 = 1.0 / sqrt(v1 + 1e-5);
    const double A0 = (double)gm[2 * l] * rs0, A1 = (double)gm[2 * l + 1] * rs1;
    const double P0 = A0 * C2, P1 = A1 * C2;
    const double Q0 = ((double)bt[2 * l] - m0 * A0) * C2;
    const double Q1 = ((double)bt[2 * l + 1] - m1 * A1) * C2;
    const float sc0 = sc[2 * l], sh0 = sh[2 * l];
    const float sc1 = sc[2 * l + 1], sh1 = sh[2 * l + 1];
    const bool last = (l == L - 1);
    double w00, w01, w10 = 0, w11 = 0, b0, b1 = 0;
    if (!last) {
      w00 = W[4 * l + 4]; w01 = W[4 * l + 5]; w10 = W[4 * l + 6]; w11 = W[4 * l + 7];
      b0 = b[2 * l + 2]; b1 = b[2 * l + 3];
    } else { w00 = Wf[0]; w01 = Wf[1]; b0 = bf[0]; }

    s0 = 0; s1 = 0; s2 = 0; s3 = 0;
#pragma unroll
    for (int r = 0; r < PRPT; ++r) {
      const int i = tid + r * TT;
      const float z0 = actf(y[r].x, P0, Q0, sc0, sh0);
      const float z1 = actf(y[r].y, P1, Q1, sc1, sh1);
      const float z2 = actf(y[r].z, P0, Q0, sc0, sh0);
      const float z3 = actf(y[r].w, P1, Q1, sc1, sh1);
      if (!last) {
        const double a0 = fma((double)z0, w00, fma((double)z1, w01, b0));
        const double a1 = fma((double)z0, w10, fma((double)z1, w11, b1));
        const double a2 = fma((double)z2, w00, fma((double)z3, w01, b0));
        const double a3 = fma((double)z2, w10, fma((double)z3, w11, b1));
        y[r] = make_float4((float)a0, (float)a1, (float)a2, (float)a3);
        if (i < N2) {
          s0 += a0 + a2; s1 += a1 + a3;
          s2 = fma(a0, a0, fma(a2, a2, s2));
          s3 = fma(a1, a1, fma(a3, a3, s3));
        }
      } else if (i < N2) {
        const double u0 = fma((double)z0, w00, fma((double)z1, w01, b0));
        const double u1 = fma((double)z2, w00, fma((double)z3, w01, b0));
        out[i] = make_float2(sigm(u0), sigm(u1));
      }
    }
    if (!last) {
      red4(acc + 4 * (l + 1), s0, s1, s2, s3);
      gbar(bar, bar + 1, PNB);
    }
  }
}

extern "C" void kernel_launch(void* const* d_in, const int* in_sizes, int n_in,
                              void* d_out, int out_size, void* d_ws, size_t ws_size,
                              hipStream_t stream) {
  const float* x  = (const float*)d_in[0];
  const float* W  = (const float*)d_in[1];
  const float* b  = (const float*)d_in[2];
  const float* gm = (const float*)d_in[3];
  const float* bt = (const float*)d_in[4];
  const float* sc = (const float*)d_in[5];
  const float* sh = (const float*)d_in[6];
  const float* Wf = (const float*)d_in[7];
  const float* bf = (const float*)d_in[8];
  const int N  = in_sizes[0] / 2;
  const int L  = in_sizes[1] / 4;
  const int N2 = N / 2;

  char* wsb = (char*)d_ws;
  double*   acc = (double*)wsb;                       // 4*L doubles (<=1536B)
  unsigned* bar = (unsigned*)(wsb + 2048);            // persistent-path barrier
  float4*   yb0 = (float4*)(wsb + 4096);
  float4*   yb1 = (float4*)(wsb + 4096 + (size_t)N2 * 16);
  const size_t need = 4096 + 2 * (size_t)N2 * 16;

  hipMemsetAsync(d_ws, 0, 4096, stream);              // zero acc + barrier

  if (ws_size >= need) {
    // 49 plain launches; kernel boundary = grid sync for the BN stats.
    layer_k<0><<<NBLK, NTHR, 0, stream>>>(
        (const float4*)x, yb0, nullptr, W, b,
        nullptr, nullptr, nullptr, nullptr, nullptr, acc, N2);
    const float4* bufs[2] = {yb0, yb1};
    for (int l = 0; l < L - 1; ++l) {
      layer_k<1><<<NBLK, NTHR, 0, stream>>>(
          bufs[l & 1], (float4*)bufs[(l + 1) & 1], nullptr,
          W + 4 * (l + 1), b + 2 * (l + 1),
          gm + 2 * l, bt + 2 * l, sc + 2 * l, sh + 2 * l,
          acc + 4 * l, acc + 4 * (l + 1), N2);
    }
    const int lf = L - 1;
    layer_k<2><<<NBLK, NTHR, 0, stream>>>(
        bufs[lf & 1], nullptr, (float2*)d_out,
        Wf, bf, gm + 2 * lf, bt + 2 * lf, sc + 2 * lf, sh + 2 * lf,
        acc + 4 * lf, nullptr, N2);
  } else {
    fraud_persist<<<PNB, PNT, 0, stream>>>(
        (const float4*)x, W, b, gm, bt, sc, sh, Wf, bf,
        (float2*)d_out, acc, bar, N2, L);
  }
}

// Round 3
// 1543.697 us; speedup vs baseline: 1.8419x; 1.8419x over previous
//
#include <hip/hip_runtime.h>

#define NB   256
#define NT   1024
#define PRPT 8
#define TT   (NB * NT)   // 262144 threads * 8 float4 = 2,097,152 >= N2

__device__ __forceinline__ float ex2(float x) { return __builtin_amdgcn_exp2f(x); }

__device__ __forceinline__ float rcp_acc(float d) {
  float r = __builtin_amdgcn_rcpf(d);
  return r * __builtin_fmaf(-d, r, 2.0f);          // 1 NR step
}
__device__ __forceinline__ float div_acc(float n, float d, float r) {
  float q = n * r;
  float rho = __builtin_fmaf(-q, d, n);
  return __builtin_fmaf(rho, r, q);
}

// BN+tanh+affine; P,Q fold BN and the 2*log2(e) tanh prescale (f64).
__device__ __forceinline__ float actf(float y, double P, double Q, float sc, float sh) {
  double u = fma((double)y, P, Q);
  float uf = (float)u;
  uf = fminf(fmaxf(uf, -60.0f), 60.0f);
  float e = ex2(uf);
  float den = e + 1.0f;
  float r = rcp_acc(den);
  float t = div_acc(e - 1.0f, den, r);             // tanh
  return __builtin_fmaf(t, sc, sh);
}

__device__ __forceinline__ float sigm(double uo) {
  const double C1 = 1.4426950408889634074;         // log2(e)
  float w = (float)(-uo * C1);
  w = fminf(fmaxf(w, -60.0f), 60.0f);
  float e = ex2(w);
  float d = 1.0f + e;
  float r = rcp_acc(d);
  return div_acc(1.0f, d, r);
}

// Reduce this block's 4 stat sums into acc[4*l..], merge with a grid barrier:
// last-arriving block finalizes stats, computes folded BN coefs (f64), publishes
// coef[4*l..] and raises flag[l]; everyone else spins on flag[l]. Returns P/Q.
__device__ __forceinline__ void layer_sync(
    int l, double s0, double s1, double s2, double s3,
    double* __restrict__ acc, double* __restrict__ coef,
    unsigned* __restrict__ cnt, unsigned* __restrict__ flag,
    const float* __restrict__ gm, const float* __restrict__ bt, double dn,
    double& P0, double& P1, double& Q0, double& Q1)
{
  __shared__ double lr[NT / 64][4];
  __shared__ double lc[4];
  const int lane = threadIdx.x & 63, wave = threadIdx.x >> 6;
#pragma unroll
  for (int off = 32; off > 0; off >>= 1) {
    s0 += __shfl_down(s0, off, 64);
    s1 += __shfl_down(s1, off, 64);
    s2 += __shfl_down(s2, off, 64);
    s3 += __shfl_down(s3, off, 64);
  }
  if (lane == 0) { lr[wave][0] = s0; lr[wave][1] = s1; lr[wave][2] = s2; lr[wave][3] = s3; }
  __syncthreads();
  if (threadIdx.x == 0) {
    double a0 = 0, a1 = 0, a2 = 0, a3 = 0;
#pragma unroll
    for (int w = 0; w < NT / 64; ++w) {
      a0 += lr[w][0]; a1 += lr[w][1]; a2 += lr[w][2]; a3 += lr[w][3];
    }
    atomicAdd(acc + 4 * l + 0, a0);
    atomicAdd(acc + 4 * l + 1, a1);
    atomicAdd(acc + 4 * l + 2, a2);
    atomicAdd(acc + 4 * l + 3, a3);
    unsigned old = __hip_atomic_fetch_add(cnt + l, 1u, __ATOMIC_ACQ_REL,
                                          __HIP_MEMORY_SCOPE_AGENT);
    if (old == (unsigned)(NB - 1)) {
      // all blocks' adds are visible (each released before its increment)
      double t0 = __hip_atomic_load(acc + 4 * l + 0, __ATOMIC_RELAXED, __HIP_MEMORY_SCOPE_AGENT);
      double t1 = __hip_atomic_load(acc + 4 * l + 1, __ATOMIC_RELAXED, __HIP_MEMORY_SCOPE_AGENT);
      double t2 = __hip_atomic_load(acc + 4 * l + 2, __ATOMIC_RELAXED, __HIP_MEMORY_SCOPE_AGENT);
      double t3 = __hip_atomic_load(acc + 4 * l + 3, __ATOMIC_RELAXED, __HIP_MEMORY_SCOPE_AGENT);
      const double m0 = t0 * dn, m1 = t1 * dn;
      const double v0 = fma(-m0, m0, t2 * dn);
      const double v1 = fma(-m1, m1, t3 * dn);
      const double rs0 = 1.0 / sqrt(v0 + 1e-5);
      const double rs1 = 1.0 / sqrt(v1 + 1e-5);
      const double A0 = (double)gm[2 * l] * rs0, A1 = (double)gm[2 * l + 1] * rs1;
      const double C2 = 2.8853900817779268147;     // 2*log2(e)
      const double p0 = A0 * C2, p1 = A1 * C2;
      const double q0 = ((double)bt[2 * l] - m0 * A0) * C2;
      const double q1 = ((double)bt[2 * l + 1] - m1 * A1) * C2;
      __hip_atomic_store(coef + 4 * l + 0, p0, __ATOMIC_RELAXED, __HIP_MEMORY_SCOPE_AGENT);
      __hip_atomic_store(coef + 4 * l + 1, p1, __ATOMIC_RELAXED, __HIP_MEMORY_SCOPE_AGENT);
      __hip_atomic_store(coef + 4 * l + 2, q0, __ATOMIC_RELAXED, __HIP_MEMORY_SCOPE_AGENT);
      __hip_atomic_store(coef + 4 * l + 3, q1, __ATOMIC_RELAXED, __HIP_MEMORY_SCOPE_AGENT);
      __hip_atomic_store(flag + l, 1u, __ATOMIC_RELEASE, __HIP_MEMORY_SCOPE_AGENT);
    }
    while (__hip_atomic_load(flag + l, __ATOMIC_ACQUIRE, __HIP_MEMORY_SCOPE_AGENT) == 0u)
      __builtin_amdgcn_s_sleep(2);
    lc[0] = __hip_atomic_load(coef + 4 * l + 0, __ATOMIC_RELAXED, __HIP_MEMORY_SCOPE_AGENT);
    lc[1] = __hip_atomic_load(coef + 4 * l + 1, __ATOMIC_RELAXED, __HIP_MEMORY_SCOPE_AGENT);
    lc[2] = __hip_atomic_load(coef + 4 * l + 2, __ATOMIC_RELAXED, __HIP_MEMORY_SCOPE_AGENT);
    lc[3] = __hip_atomic_load(coef + 4 * l + 3, __ATOMIC_RELAXED, __HIP_MEMORY_SCOPE_AGENT);
  }
  __syncthreads();
  P0 = lc[0]; P1 = lc[1]; Q0 = lc[2]; Q1 = lc[3];
}

__global__ __launch_bounds__(NT, 4) void fraud_persist(
    const float4* __restrict__ x, const float* __restrict__ W,
    const float* __restrict__ b, const float* __restrict__ gm,
    const float* __restrict__ bt, const float* __restrict__ sc,
    const float* __restrict__ sh, const float* __restrict__ Wf,
    const float* __restrict__ bf, float2* __restrict__ out,
    double* __restrict__ acc, double* __restrict__ coef,
    unsigned* __restrict__ cnt, unsigned* __restrict__ flag, int N2, int L)
{
  const int tid = blockIdx.x * NT + threadIdx.x;
  float4 y[PRPT];                                  // activations live here all 48 layers
  double s0 = 0, s1 = 0, s2 = 0, s3 = 0;

  // ---- pass 0: y0 = W0 x + b0 (+ stats of y0) ----
  {
    const double w00 = W[0], w01 = W[1], w10 = W[2], w11 = W[3];
    const double b0 = b[0], b1 = b[1];
#pragma unroll
    for (int r = 0; r < PRPT; ++r) {
      const int i = tid + r * TT;
      const float4 p = (i < N2) ? x[i] : make_float4(0.f, 0.f, 0.f, 0.f);
      const double a0 = fma((double)p.x, w00, fma((double)p.y, w01, b0));
      const double a1 = fma((double)p.x, w10, fma((double)p.y, w11, b1));
      const double a2 = fma((double)p.z, w00, fma((double)p.w, w01, b0));
      const double a3 = fma((double)p.z, w10, fma((double)p.w, w11, b1));
      y[r] = make_float4((float)a0, (float)a1, (float)a2, (float)a3);
      if (i < N2) {
        s0 += a0 + a2; s1 += a1 + a3;
        s2 = fma(a0, a0, fma(a2, a2, s2));
        s3 = fma(a1, a1, fma(a3, a3, s3));
      }
    }
  }
  const double dn = 0.5 / (double)N2;              // 1/N
  double P0, P1, Q0, Q1;
  layer_sync(0, s0, s1, s2, s3, acc, coef, cnt, flag, gm, bt, dn, P0, P1, Q0, Q1);

  for (int l = 0; l < L; ++l) {
    const float sc0 = sc[2 * l], sh0 = sh[2 * l];
    const float sc1 = sc[2 * l + 1], sh1 = sh[2 * l + 1];
    const bool last = (l == L - 1);
    double w00, w01, w10 = 0, w11 = 0, b0, b1 = 0;
    if (!last) {
      w00 = W[4 * l + 4]; w01 = W[4 * l + 5]; w10 = W[4 * l + 6]; w11 = W[4 * l + 7];
      b0 = b[2 * l + 2]; b1 = b[2 * l + 3];
    } else { w00 = Wf[0]; w01 = Wf[1]; b0 = bf[0]; }

    s0 = 0; s1 = 0; s2 = 0; s3 = 0;
#pragma unroll
    for (int r = 0; r < PRPT; ++r) {
      const int i = tid + r * TT;
      const float z0 = actf(y[r].x, P0, Q0, sc0, sh0);
      const float z1 = actf(y[r].y, P1, Q1, sc1, sh1);
      const float z2 = actf(y[r].z, P0, Q0, sc0, sh0);
      const float z3 = actf(y[r].w, P1, Q1, sc1, sh1);
      if (!last) {
        const double a0 = fma((double)z0, w00, fma((double)z1, w01, b0));
        const double a1 = fma((double)z0, w10, fma((double)z1, w11, b1));
        const double a2 = fma((double)z2, w00, fma((double)z3, w01, b0));
        const double a3 = fma((double)z2, w10, fma((double)z3, w11, b1));
        y[r] = make_float4((float)a0, (float)a1, (float)a2, (float)a3);
        if (i < N2) {
          s0 += a0 + a2; s1 += a1 + a3;
          s2 = fma(a0, a0, fma(a2, a2, s2));
          s3 = fma(a1, a1, fma(a3, a3, s3));
        }
      } else if (i < N2) {
        const double u0 = fma((double)z0, w00, fma((double)z1, w01, b0));
        const double u1 = fma((double)z2, w00, fma((double)z3, w01, b0));
        out[i] = make_float2(sigm(u0), sigm(u1));
      }
    }
    if (!last) {
      layer_sync(l + 1, s0, s1, s2, s3, acc, coef, cnt, flag, gm, bt, dn,
                 P0, P1, Q0, Q1);
    }
  }
}

extern "C" void kernel_launch(void* const* d_in, const int* in_sizes, int n_in,
                              void* d_out, int out_size, void* d_ws, size_t ws_size,
                              hipStream_t stream) {
  const float* x  = (const float*)d_in[0];
  const float* W  = (const float*)d_in[1];
  const float* b  = (const float*)d_in[2];
  const float* gm = (const float*)d_in[3];
  const float* bt = (const float*)d_in[4];
  const float* sc = (const float*)d_in[5];
  const float* sh = (const float*)d_in[6];
  const float* Wf = (const float*)d_in[7];
  const float* bf = (const float*)d_in[8];
  const int N  = in_sizes[0] / 2;
  const int L  = in_sizes[1] / 4;   // 48
  const int N2 = N / 2;             // float4 count (2 rows each)

  char* wsb = (char*)d_ws;
  double*   acc  = (double*)(wsb);            // L*4 doubles
  double*   coef = (double*)(wsb + 4096);     // L*4 doubles (P0,P1,Q0,Q1)
  unsigned* cnt  = (unsigned*)(wsb + 8192);   // L counters
  unsigned* flag = (unsigned*)(wsb + 12288);  // L flags

  hipMemsetAsync(d_ws, 0, 16384, stream);

  fraud_persist<<<NB, NT, 0, stream>>>(
      (const float4*)x, W, b, gm, bt, sc, sh, Wf, bf,
      (float2*)d_out, acc, coef, cnt, flag, N2, L);
}

// Round 4
// 1298.301 us; speedup vs baseline: 2.1900x; 1.1890x over previous
//
#include <hip/hip_runtime.h>

#define NB   256
#define NT   1024
#define PRPT 8
#define TT   (NB * NT)   // 262144 threads * 8 float4 (2 rows each) covers N=4M

struct alignas(64) Slot { double s[4]; unsigned flag; unsigned pad[3]; };
struct alignas(64) Coef { double c[4]; unsigned flag; unsigned pad[3]; };

__device__ __forceinline__ float ex2(float x) { return __builtin_amdgcn_exp2f(x); }

__device__ __forceinline__ float rcp_acc(float d) {
  float r = __builtin_amdgcn_rcpf(d);
  return r * __builtin_fmaf(-d, r, 2.0f);          // 1 NR step
}
__device__ __forceinline__ float div_acc(float n, float d, float r) {
  float q = n * r;
  float rho = __builtin_fmaf(-q, d, n);
  return __builtin_fmaf(rho, r, q);
}

// BN+tanh+affine; P,Q fold BN and the 2*log2(e) tanh prescale (f64).
__device__ __forceinline__ float actf(float y, double P, double Q, float sc, float sh) {
  double u = fma((double)y, P, Q);
  float uf = (float)u;
  uf = fminf(fmaxf(uf, -60.0f), 60.0f);
  float e = ex2(uf);
  float den = e + 1.0f;
  float r = rcp_acc(den);
  float t = div_acc(e - 1.0f, den, r);             // tanh
  return __builtin_fmaf(t, sc, sh);
}

__device__ __forceinline__ float sigm(double uo) {
  const double C1 = 1.4426950408889634074;         // log2(e)
  float w = (float)(-uo * C1);
  w = fminf(fmaxf(w, -60.0f), 60.0f);
  float e = ex2(w);
  float d = 1.0f + e;
  float r = rcp_acc(d);
  return div_acc(1.0f, d, r);
}

// Contention-free grid barrier + stats broadcast.
// Hop 1: each block release-stores 4 f64 partials to its OWN 64B slot (flag=l+1).
// Hop 2: block 0 (threads 0..NB-1) polls all slots in parallel, reduces,
//        computes folded BN coefs in f64, publishes one coef line (flag!=0).
// Everyone spins on the read-only coef line. No atomic RMW anywhere.
__device__ __forceinline__ void layer_sync(
    int l, double s0, double s1, double s2, double s3,
    Coef* __restrict__ coef, Slot* __restrict__ slot,
    const float* __restrict__ gm, const float* __restrict__ bt, double dn,
    double& P0, double& P1, double& Q0, double& Q1)
{
  __shared__ double lr[NT / 64][4];
  __shared__ double lg[4][4];
  __shared__ double lc[4];
  const int lane = threadIdx.x & 63, wave = threadIdx.x >> 6;

  // intra-block reduce (identical structure/order to the passing kernel)
#pragma unroll
  for (int off = 32; off > 0; off >>= 1) {
    s0 += __shfl_down(s0, off, 64);
    s1 += __shfl_down(s1, off, 64);
    s2 += __shfl_down(s2, off, 64);
    s3 += __shfl_down(s3, off, 64);
  }
  if (lane == 0) { lr[wave][0] = s0; lr[wave][1] = s1; lr[wave][2] = s2; lr[wave][3] = s3; }
  __syncthreads();
  if (threadIdx.x == 0) {
    double a0 = 0, a1 = 0, a2 = 0, a3 = 0;
#pragma unroll
    for (int w = 0; w < NT / 64; ++w) {
      a0 += lr[w][0]; a1 += lr[w][1]; a2 += lr[w][2]; a3 += lr[w][3];
    }
    Slot* my = slot + blockIdx.x;
    __hip_atomic_store(&my->s[0], a0, __ATOMIC_RELAXED, __HIP_MEMORY_SCOPE_AGENT);
    __hip_atomic_store(&my->s[1], a1, __ATOMIC_RELAXED, __HIP_MEMORY_SCOPE_AGENT);
    __hip_atomic_store(&my->s[2], a2, __ATOMIC_RELAXED, __HIP_MEMORY_SCOPE_AGENT);
    __hip_atomic_store(&my->s[3], a3, __ATOMIC_RELAXED, __HIP_MEMORY_SCOPE_AGENT);
    __hip_atomic_store(&my->flag, (unsigned)(l + 1), __ATOMIC_RELEASE, __HIP_MEMORY_SCOPE_AGENT);
  }

  if (blockIdx.x == 0) {
    double g0 = 0, g1 = 0, g2 = 0, g3 = 0;
    if (threadIdx.x < NB) {
      Slot* sl = slot + threadIdx.x;
      while (__hip_atomic_load(&sl->flag, __ATOMIC_ACQUIRE, __HIP_MEMORY_SCOPE_AGENT)
             != (unsigned)(l + 1))
        __builtin_amdgcn_s_sleep(1);
      g0 = __hip_atomic_load(&sl->s[0], __ATOMIC_RELAXED, __HIP_MEMORY_SCOPE_AGENT);
      g1 = __hip_atomic_load(&sl->s[1], __ATOMIC_RELAXED, __HIP_MEMORY_SCOPE_AGENT);
      g2 = __hip_atomic_load(&sl->s[2], __ATOMIC_RELAXED, __HIP_MEMORY_SCOPE_AGENT);
      g3 = __hip_atomic_load(&sl->s[3], __ATOMIC_RELAXED, __HIP_MEMORY_SCOPE_AGENT);
#pragma unroll
      for (int off = 32; off > 0; off >>= 1) {
        g0 += __shfl_down(g0, off, 64);
        g1 += __shfl_down(g1, off, 64);
        g2 += __shfl_down(g2, off, 64);
        g3 += __shfl_down(g3, off, 64);
      }
      if (lane == 0) { lg[wave][0] = g0; lg[wave][1] = g1; lg[wave][2] = g2; lg[wave][3] = g3; }
    }
    __syncthreads();
    if (threadIdx.x == 0) {
      const double t0 = lg[0][0] + lg[1][0] + lg[2][0] + lg[3][0];
      const double t1 = lg[0][1] + lg[1][1] + lg[2][1] + lg[3][1];
      const double t2 = lg[0][2] + lg[1][2] + lg[2][2] + lg[3][2];
      const double t3 = lg[0][3] + lg[1][3] + lg[2][3] + lg[3][3];
      const double m0 = t0 * dn, m1 = t1 * dn;
      const double v0 = fma(-m0, m0, t2 * dn);
      const double v1 = fma(-m1, m1, t3 * dn);
      const double rs0 = 1.0 / sqrt(v0 + 1e-5);
      const double rs1 = 1.0 / sqrt(v1 + 1e-5);
      const double A0 = (double)gm[2 * l] * rs0, A1 = (double)gm[2 * l + 1] * rs1;
      const double C2 = 2.8853900817779268147;     // 2*log2(e)
      Coef* cf = coef + l;
      __hip_atomic_store(&cf->c[0], A0 * C2, __ATOMIC_RELAXED, __HIP_MEMORY_SCOPE_AGENT);
      __hip_atomic_store(&cf->c[1], A1 * C2, __ATOMIC_RELAXED, __HIP_MEMORY_SCOPE_AGENT);
      __hip_atomic_store(&cf->c[2], ((double)bt[2 * l] - m0 * A0) * C2, __ATOMIC_RELAXED, __HIP_MEMORY_SCOPE_AGENT);
      __hip_atomic_store(&cf->c[3], ((double)bt[2 * l + 1] - m1 * A1) * C2, __ATOMIC_RELAXED, __HIP_MEMORY_SCOPE_AGENT);
      __hip_atomic_store(&cf->flag, 1u, __ATOMIC_RELEASE, __HIP_MEMORY_SCOPE_AGENT);
    }
  }

  if (threadIdx.x == 0) {
    Coef* cf = coef + l;
    while (__hip_atomic_load(&cf->flag, __ATOMIC_ACQUIRE, __HIP_MEMORY_SCOPE_AGENT) == 0u)
      __builtin_amdgcn_s_sleep(8);
    lc[0] = __hip_atomic_load(&cf->c[0], __ATOMIC_RELAXED, __HIP_MEMORY_SCOPE_AGENT);
    lc[1] = __hip_atomic_load(&cf->c[1], __ATOMIC_RELAXED, __HIP_MEMORY_SCOPE_AGENT);
    lc[2] = __hip_atomic_load(&cf->c[2], __ATOMIC_RELAXED, __HIP_MEMORY_SCOPE_AGENT);
    lc[3] = __hip_atomic_load(&cf->c[3], __ATOMIC_RELAXED, __HIP_MEMORY_SCOPE_AGENT);
  }
  __syncthreads();
  P0 = lc[0]; P1 = lc[1]; Q0 = lc[2]; Q1 = lc[3];
}

__global__ __launch_bounds__(NT, 4) void fraud_persist(
    const float4* __restrict__ x, const float* __restrict__ W,
    const float* __restrict__ b, const float* __restrict__ gm,
    const float* __restrict__ bt, const float* __restrict__ sc,
    const float* __restrict__ sh, const float* __restrict__ Wf,
    const float* __restrict__ bf, float2* __restrict__ out,
    Coef* __restrict__ coef, Slot* __restrict__ slot, int N2, int L)
{
  const int tid = blockIdx.x * NT + threadIdx.x;
  float4 y[PRPT];                                  // activations live in registers all layers
  double s0 = 0, s1 = 0, s2 = 0, s3 = 0;

  // ---- pass 0: y0 = W0 x + b0 (+ stats of y0) ----
  {
    const double w00 = W[0], w01 = W[1], w10 = W[2], w11 = W[3];
    const double b0 = b[0], b1 = b[1];
#pragma unroll
    for (int r = 0; r < PRPT; ++r) {
      const int i = tid + r * TT;
      const float4 p = (i < N2) ? x[i] : make_float4(0.f, 0.f, 0.f, 0.f);
      const double a0 = fma((double)p.x, w00, fma((double)p.y, w01, b0));
      const double a1 = fma((double)p.x, w10, fma((double)p.y, w11, b1));
      const double a2 = fma((double)p.z, w00, fma((double)p.w, w01, b0));
      const double a3 = fma((double)p.z, w10, fma((double)p.w, w11, b1));
      y[r] = make_float4((float)a0, (float)a1, (float)a2, (float)a3);
      if (i < N2) {
        s0 += a0 + a2; s1 += a1 + a3;
        s2 = fma(a0, a0, fma(a2, a2, s2));
        s3 = fma(a1, a1, fma(a3, a3, s3));
      }
    }
  }
  const double dn = 0.5 / (double)N2;              // 1/N
  double P0, P1, Q0, Q1;
  layer_sync(0, s0, s1, s2, s3, coef, slot, gm, bt, dn, P0, P1, Q0, Q1);

  for (int l = 0; l < L; ++l) {
    const float sc0 = sc[2 * l], sh0 = sh[2 * l];
    const float sc1 = sc[2 * l + 1], sh1 = sh[2 * l + 1];
    const bool last = (l == L - 1);
    double w00, w01, w10 = 0, w11 = 0, b0, b1 = 0;
    if (!last) {
      w00 = W[4 * l + 4]; w01 = W[4 * l + 5]; w10 = W[4 * l + 6]; w11 = W[4 * l + 7];
      b0 = b[2 * l + 2]; b1 = b[2 * l + 3];
    } else { w00 = Wf[0]; w01 = Wf[1]; b0 = bf[0]; }

    s0 = 0; s1 = 0; s2 = 0; s3 = 0;
#pragma unroll
    for (int r = 0; r < PRPT; ++r) {
      const int i = tid + r * TT;
      const float z0 = actf(y[r].x, P0, Q0, sc0, sh0);
      const float z1 = actf(y[r].y, P1, Q1, sc1, sh1);
      const float z2 = actf(y[r].z, P0, Q0, sc0, sh0);
      const float z3 = actf(y[r].w, P1, Q1, sc1, sh1);
      if (!last) {
        const double a0 = fma((double)z0, w00, fma((double)z1, w01, b0));
        const double a1 = fma((double)z0, w10, fma((double)z1, w11, b1));
        const double a2 = fma((double)z2, w00, fma((double)z3, w01, b0));
        const double a3 = fma((double)z2, w10, fma((double)z3, w11, b1));
        y[r] = make_float4((float)a0, (float)a1, (float)a2, (float)a3);
        if (i < N2) {
          s0 += a0 + a2; s1 += a1 + a3;
          s2 = fma(a0, a0, fma(a2, a2, s2));
          s3 = fma(a1, a1, fma(a3, a3, s3));
        }
      } else if (i < N2) {
        const double u0 = fma((double)z0, w00, fma((double)z1, w01, b0));
        const double u1 = fma((double)z2, w00, fma((double)z3, w01, b0));
        out[i] = make_float2(sigm(u0), sigm(u1));
      }
    }
    if (!last) {
      layer_sync(l + 1, s0, s1, s2, s3, coef, slot, gm, bt, dn, P0, P1, Q0, Q1);
    }
  }
}

extern "C" void kernel_launch(void* const* d_in, const int* in_sizes, int n_in,
                              void* d_out, int out_size, void* d_ws, size_t ws_size,
                              hipStream_t stream) {
  const float* x  = (const float*)d_in[0];
  const float* W  = (const float*)d_in[1];
  const float* b  = (const float*)d_in[2];
  const float* gm = (const float*)d_in[3];
  const float* bt = (const float*)d_in[4];
  const float* sc = (const float*)d_in[5];
  const float* sh = (const float*)d_in[6];
  const float* Wf = (const float*)d_in[7];
  const float* bf = (const float*)d_in[8];
  const int N  = in_sizes[0] / 2;
  const int L  = in_sizes[1] / 4;   // 48
  const int N2 = N / 2;             // float4 count (2 rows each)

  char* wsb = (char*)d_ws;
  Coef* coef = (Coef*)wsb;                 // 48 * 64B
  Slot* slot = (Slot*)(wsb + 4096);        // 256 * 64B

  hipMemsetAsync(d_ws, 0, 4096 + NB * sizeof(Slot), stream);  // zero flags

  fraud_persist<<<NB, NT, 0, stream>>>(
      (const float4*)x, W, b, gm, bt, sc, sh, Wf, bf,
      (float2*)d_out, coef, slot, N2, L);
}

// Round 5
// 865.765 us; speedup vs baseline: 3.2841x; 1.4996x over previous
//
#include <hip/hip_runtime.h>

#define NB   256
#define NT   1024
#define PRPT 8
#define TT   (NB * NT)   // 262144 threads * 8 float4 (2 rows each) covers N=4M

struct alignas(128) Slot { double s[4]; unsigned flag; unsigned pad[23]; };  // one 128B line

__device__ __forceinline__ float ex2(float x) { return __builtin_amdgcn_exp2f(x); }

__device__ __forceinline__ float rcp_acc(float d) {
  float r = __builtin_amdgcn_rcpf(d);
  return r * __builtin_fmaf(-d, r, 2.0f);          // 1 NR step
}
__device__ __forceinline__ float div_acc(float n, float d, float r) {
  float q = n * r;
  float rho = __builtin_fmaf(-q, d, n);
  return __builtin_fmaf(rho, r, q);
}

// BN+tanh+affine; P,Q fold BN and the 2*log2(e) tanh prescale (f64).
__device__ __forceinline__ float actf(float y, double P, double Q, float sc, float sh) {
  double u = fma((double)y, P, Q);
  float uf = (float)u;
  uf = fminf(fmaxf(uf, -60.0f), 60.0f);
  float e = ex2(uf);
  float den = e + 1.0f;
  float r = rcp_acc(den);
  float t = div_acc(e - 1.0f, den, r);             // tanh
  return __builtin_fmaf(t, sc, sh);
}

__device__ __forceinline__ float sigm(double uo) {
  const double C1 = 1.4426950408889634074;         // log2(e)
  float w = (float)(-uo * C1);
  w = fminf(fmaxf(w, -60.0f), 60.0f);
  float e = ex2(w);
  float d = 1.0f + e;
  float r = rcp_acc(d);
  return div_acc(1.0f, d, r);
}

// Flat all-to-all barrier + stats exchange. Every block:
//  1) release-publishes its 4 f64 partials to its own 128B slot (parity-buffered),
//  2) threads 0..255 RELAXED-poll all 256 slots (no per-iteration cache inv!),
//  3) one acquire fence after detection, re-load values cache-bypassed,
//  4) reduces locally (identical order in every block -> bit-identical stats),
//     computes folded BN coefs in f64, broadcasts via LDS.
__device__ __forceinline__ void layer_sync(
    int l, double s0, double s1, double s2, double s3,
    Slot* __restrict__ slot,
    const float* __restrict__ gm, const float* __restrict__ bt, double dn,
    double& P0, double& P1, double& Q0, double& Q1)
{
  __shared__ double lr[NT / 64][4];
  __shared__ double lg[4][4];
  __shared__ double lc[4];
  const int lane = threadIdx.x & 63, wave = threadIdx.x >> 6;

  // intra-block reduce (identical structure/order to the passing kernel)
#pragma unroll
  for (int off = 32; off > 0; off >>= 1) {
    s0 += __shfl_down(s0, off, 64);
    s1 += __shfl_down(s1, off, 64);
    s2 += __shfl_down(s2, off, 64);
    s3 += __shfl_down(s3, off, 64);
  }
  if (lane == 0) { lr[wave][0] = s0; lr[wave][1] = s1; lr[wave][2] = s2; lr[wave][3] = s3; }
  __syncthreads();

  Slot* sb = slot + (size_t)(l & 1) * NB;          // parity buffer: no overwrite races
  if (threadIdx.x == 0) {
    double a0 = 0, a1 = 0, a2 = 0, a3 = 0;
#pragma unroll
    for (int w = 0; w < NT / 64; ++w) {
      a0 += lr[w][0]; a1 += lr[w][1]; a2 += lr[w][2]; a3 += lr[w][3];
    }
    Slot* my = sb + blockIdx.x;
    __hip_atomic_store(&my->s[0], a0, __ATOMIC_RELAXED, __HIP_MEMORY_SCOPE_AGENT);
    __hip_atomic_store(&my->s[1], a1, __ATOMIC_RELAXED, __HIP_MEMORY_SCOPE_AGENT);
    __hip_atomic_store(&my->s[2], a2, __ATOMIC_RELAXED, __HIP_MEMORY_SCOPE_AGENT);
    __hip_atomic_store(&my->s[3], a3, __ATOMIC_RELAXED, __HIP_MEMORY_SCOPE_AGENT);
    // hardware-level release: data stores complete at coherence point, then flag
    asm volatile("s_waitcnt vmcnt(0)" ::: "memory");
    __hip_atomic_store(&my->flag, (unsigned)(l + 1), __ATOMIC_RELAXED, __HIP_MEMORY_SCOPE_AGENT);
  }

  if (threadIdx.x < NB) {
    Slot* sl = sb + threadIdx.x;
    // RELAXED polling: cache-bypassing load straight from L3, NO buffer_inv per probe
    while (__hip_atomic_load(&sl->flag, __ATOMIC_RELAXED, __HIP_MEMORY_SCOPE_AGENT)
           != (unsigned)(l + 1))
      __builtin_amdgcn_s_sleep(1);
    __builtin_amdgcn_fence(__ATOMIC_ACQUIRE, "agent");   // one inv per wave per layer
    double g0 = __hip_atomic_load(&sl->s[0], __ATOMIC_RELAXED, __HIP_MEMORY_SCOPE_AGENT);
    double g1 = __hip_atomic_load(&sl->s[1], __ATOMIC_RELAXED, __HIP_MEMORY_SCOPE_AGENT);
    double g2 = __hip_atomic_load(&sl->s[2], __ATOMIC_RELAXED, __HIP_MEMORY_SCOPE_AGENT);
    double g3 = __hip_atomic_load(&sl->s[3], __ATOMIC_RELAXED, __HIP_MEMORY_SCOPE_AGENT);
#pragma unroll
    for (int off = 32; off > 0; off >>= 1) {
      g0 += __shfl_down(g0, off, 64);
      g1 += __shfl_down(g1, off, 64);
      g2 += __shfl_down(g2, off, 64);
      g3 += __shfl_down(g3, off, 64);
    }
    if (lane == 0) { lg[wave][0] = g0; lg[wave][1] = g1; lg[wave][2] = g2; lg[wave][3] = g3; }
  }
  __syncthreads();
  if (threadIdx.x == 0) {
    const double t0 = lg[0][0] + lg[1][0] + lg[2][0] + lg[3][0];
    const double t1 = lg[0][1] + lg[1][1] + lg[2][1] + lg[3][1];
    const double t2 = lg[0][2] + lg[1][2] + lg[2][2] + lg[3][2];
    const double t3 = lg[0][3] + lg[1][3] + lg[2][3] + lg[3][3];
    const double m0 = t0 * dn, m1 = t1 * dn;
    const double v0 = fma(-m0, m0, t2 * dn);
    const double v1 = fma(-m1, m1, t3 * dn);
    const double rs0 = 1.0 / sqrt(v0 + 1e-5);
    const double rs1 = 1.0 / sqrt(v1 + 1e-5);
    const double A0 = (double)gm[2 * l] * rs0, A1 = (double)gm[2 * l + 1] * rs1;
    const double C2 = 2.8853900817779268147;       // 2*log2(e)
    lc[0] = A0 * C2;
    lc[1] = A1 * C2;
    lc[2] = ((double)bt[2 * l] - m0 * A0) * C2;
    lc[3] = ((double)bt[2 * l + 1] - m1 * A1) * C2;
  }
  __syncthreads();
  P0 = lc[0]; P1 = lc[1]; Q0 = lc[2]; Q1 = lc[3];
}

__global__ __launch_bounds__(NT, 4) void fraud_persist(
    const float4* __restrict__ x, const float* __restrict__ W,
    const float* __restrict__ b, const float* __restrict__ gm,
    const float* __restrict__ bt, const float* __restrict__ sc,
    const float* __restrict__ sh, const float* __restrict__ Wf,
    const float* __restrict__ bf, float2* __restrict__ out,
    Slot* __restrict__ slot, int N2, int L)
{
  const int tid = blockIdx.x * NT + threadIdx.x;
  float4 y[PRPT];                                  // activations live in registers all layers
  double s0 = 0, s1 = 0, s2 = 0, s3 = 0;

  // ---- pass 0: y0 = W0 x + b0 (+ stats of y0) ----
  {
    const double w00 = W[0], w01 = W[1], w10 = W[2], w11 = W[3];
    const double b0 = b[0], b1 = b[1];
#pragma unroll
    for (int r = 0; r < PRPT; ++r) {
      const int i = tid + r * TT;
      const float4 p = (i < N2) ? x[i] : make_float4(0.f, 0.f, 0.f, 0.f);
      const double a0 = fma((double)p.x, w00, fma((double)p.y, w01, b0));
      const double a1 = fma((double)p.x, w10, fma((double)p.y, w11, b1));
      const double a2 = fma((double)p.z, w00, fma((double)p.w, w01, b0));
      const double a3 = fma((double)p.z, w10, fma((double)p.w, w11, b1));
      y[r] = make_float4((float)a0, (float)a1, (float)a2, (float)a3);
      if (i < N2) {
        s0 += a0 + a2; s1 += a1 + a3;
        s2 = fma(a0, a0, fma(a2, a2, s2));
        s3 = fma(a1, a1, fma(a3, a3, s3));
      }
    }
  }
  const double dn = 0.5 / (double)N2;              // 1/N
  double P0, P1, Q0, Q1;
  layer_sync(0, s0, s1, s2, s3, slot, gm, bt, dn, P0, P1, Q0, Q1);

  for (int l = 0; l < L; ++l) {
    const float sc0 = sc[2 * l], sh0 = sh[2 * l];
    const float sc1 = sc[2 * l + 1], sh1 = sh[2 * l + 1];
    const bool last = (l == L - 1);
    double w00, w01, w10 = 0, w11 = 0, b0, b1 = 0;
    if (!last) {
      w00 = W[4 * l + 4]; w01 = W[4 * l + 5]; w10 = W[4 * l + 6]; w11 = W[4 * l + 7];
      b0 = b[2 * l + 2]; b1 = b[2 * l + 3];
    } else { w00 = Wf[0]; w01 = Wf[1]; b0 = bf[0]; }

    s0 = 0; s1 = 0; s2 = 0; s3 = 0;
#pragma unroll
    for (int r = 0; r < PRPT; ++r) {
      const int i = tid + r * TT;
      const float z0 = actf(y[r].x, P0, Q0, sc0, sh0);
      const float z1 = actf(y[r].y, P1, Q1, sc1, sh1);
      const float z2 = actf(y[r].z, P0, Q0, sc0, sh0);
      const float z3 = actf(y[r].w, P1, Q1, sc1, sh1);
      if (!last) {
        const double a0 = fma((double)z0, w00, fma((double)z1, w01, b0));
        const double a1 = fma((double)z0, w10, fma((double)z1, w11, b1));
        const double a2 = fma((double)z2, w00, fma((double)z3, w01, b0));
        const double a3 = fma((double)z2, w10, fma((double)z3, w11, b1));
        y[r] = make_float4((float)a0, (float)a1, (float)a2, (float)a3);
        if (i < N2) {
          s0 += a0 + a2; s1 += a1 + a3;
          s2 = fma(a0, a0, fma(a2, a2, s2));
          s3 = fma(a1, a1, fma(a3, a3, s3));
        }
      } else if (i < N2) {
        const double u0 = fma((double)z0, w00, fma((double)z1, w01, b0));
        const double u1 = fma((double)z2, w00, fma((double)z3, w01, b0));
        out[i] = make_float2(sigm(u0), sigm(u1));
      }
    }
    if (!last) {
      layer_sync(l + 1, s0, s1, s2, s3, slot, gm, bt, dn, P0, P1, Q0, Q1);
    }
  }
}

extern "C" void kernel_launch(void* const* d_in, const int* in_sizes, int n_in,
                              void* d_out, int out_size, void* d_ws, size_t ws_size,
                              hipStream_t stream) {
  const float* x  = (const float*)d_in[0];
  const float* W  = (const float*)d_in[1];
  const float* b  = (const float*)d_in[2];
  const float* gm = (const float*)d_in[3];
  const float* bt = (const float*)d_in[4];
  const float* sc = (const float*)d_in[5];
  const float* sh = (const float*)d_in[6];
  const float* Wf = (const float*)d_in[7];
  const float* bf = (const float*)d_in[8];
  const int N  = in_sizes[0] / 2;
  const int L  = in_sizes[1] / 4;   // 48
  const int N2 = N / 2;             // float4 count (2 rows each)

  Slot* slot = (Slot*)d_ws;                        // 2 (parity) * NB slots * 128B = 64KB

  hipMemsetAsync(d_ws, 0, 2 * NB * sizeof(Slot), stream);  // zero flags each call

  fraud_persist<<<NB, NT, 0, stream>>>(
      (const float4*)x, W, b, gm, bt, sc, sh, Wf, bf,
      (float2*)d_out, slot, N2, L);
}

// Round 6
// 532.353 us; speedup vs baseline: 5.3410x; 1.6263x over previous
//
#include <hip/hip_runtime.h>

#define NB   256
#define NT   1024
#define PRPT 8
#define TT   (NB * NT)   // 262144 threads * 8 float4 (2 rows each) covers N=4M

struct alignas(128) Slot { double s[4]; unsigned flag; unsigned pad[23]; };  // one 128B line

__device__ __forceinline__ float ex2(float x) { return __builtin_amdgcn_exp2f(x); }

__device__ __forceinline__ float rcp_acc(float d) {
  float r = __builtin_amdgcn_rcpf(d);
  return r * __builtin_fmaf(-d, r, 2.0f);          // 1 NR step
}
__device__ __forceinline__ float div_acc(float n, float d, float r) {
  float q = n * r;
  float rho = __builtin_fmaf(-q, d, n);
  return __builtin_fmaf(rho, r, q);
}

// BN+tanh+affine; P,Q fold BN and the 2*log2(e) tanh prescale (f64).
__device__ __forceinline__ float actf(float y, double P, double Q, float sc, float sh) {
  double u = fma((double)y, P, Q);
  float uf = (float)u;
  uf = fminf(fmaxf(uf, -60.0f), 60.0f);
  float e = ex2(uf);
  float den = e + 1.0f;
  float r = rcp_acc(den);
  float t = div_acc(e - 1.0f, den, r);             // tanh
  return __builtin_fmaf(t, sc, sh);
}

__device__ __forceinline__ float sigm(double uo) {
  const double C1 = 1.4426950408889634074;         // log2(e)
  float w = (float)(-uo * C1);
  w = fminf(fmaxf(w, -60.0f), 60.0f);
  float e = ex2(w);
  float d = 1.0f + e;
  float r = rcp_acc(d);
  return div_acc(1.0f, d, r);
}

// Fence-free all-to-all barrier + stats exchange.
// Writer: 4 agent-scope relaxed stores (sc1, land in L3), s_waitcnt vmcnt(0),
//         then flag store to the SAME 128B line.
// Reader: relaxed-polls the flag (sc1 load, no cache invalidate ever); data
//         loads are issued only after the flag value resolves the branch, so
//         they reach L3 after the flag did -> data guaranteed present.
// NO acquire fence anywhere -> zero buffer_inv, caches stay warm.
__device__ __forceinline__ void layer_sync(
    int l, double s0, double s1, double s2, double s3,
    Slot* __restrict__ slot,
    float gmv0, float gmv1, float btv0, float btv1, double dn,
    double& P0, double& P1, double& Q0, double& Q1)
{
  __shared__ double lr[NT / 64][4];
  __shared__ double lg[4][4];
  __shared__ double lc[4];
  const int lane = threadIdx.x & 63, wave = threadIdx.x >> 6;

  // intra-wave reduce
#pragma unroll
  for (int off = 32; off > 0; off >>= 1) {
    s0 += __shfl_down(s0, off, 64);
    s1 += __shfl_down(s1, off, 64);
    s2 += __shfl_down(s2, off, 64);
    s3 += __shfl_down(s3, off, 64);
  }
  if (lane == 0) { lr[wave][0] = s0; lr[wave][1] = s1; lr[wave][2] = s2; lr[wave][3] = s3; }
  __syncthreads();

  Slot* sb = slot + (size_t)(l & 1) * NB;          // parity buffer: no overwrite races
  // parallel block-partial sum (16 lanes + shuffle tree) + publish
  if (threadIdx.x < NT / 64) {
    double a0 = lr[threadIdx.x][0], a1 = lr[threadIdx.x][1];
    double a2 = lr[threadIdx.x][2], a3 = lr[threadIdx.x][3];
#pragma unroll
    for (int off = 8; off > 0; off >>= 1) {
      a0 += __shfl_down(a0, off, 64);
      a1 += __shfl_down(a1, off, 64);
      a2 += __shfl_down(a2, off, 64);
      a3 += __shfl_down(a3, off, 64);
    }
    if (threadIdx.x == 0) {
      Slot* my = sb + blockIdx.x;
      __hip_atomic_store(&my->s[0], a0, __ATOMIC_RELAXED, __HIP_MEMORY_SCOPE_AGENT);
      __hip_atomic_store(&my->s[1], a1, __ATOMIC_RELAXED, __HIP_MEMORY_SCOPE_AGENT);
      __hip_atomic_store(&my->s[2], a2, __ATOMIC_RELAXED, __HIP_MEMORY_SCOPE_AGENT);
      __hip_atomic_store(&my->s[3], a3, __ATOMIC_RELAXED, __HIP_MEMORY_SCOPE_AGENT);
      asm volatile("s_waitcnt vmcnt(0)" ::: "memory");   // data lands before flag
      __hip_atomic_store(&my->flag, (unsigned)(l + 1), __ATOMIC_RELAXED, __HIP_MEMORY_SCOPE_AGENT);
    }
  }

  if (threadIdx.x < NB) {
    Slot* sl = sb + threadIdx.x;
    while (__hip_atomic_load(&sl->flag, __ATOMIC_RELAXED, __HIP_MEMORY_SCOPE_AGENT)
           != (unsigned)(l + 1))
      __builtin_amdgcn_s_sleep(1);
    asm volatile("" ::: "memory");                 // pin program order, no cache inv
    double g0 = __hip_atomic_load(&sl->s[0], __ATOMIC_RELAXED, __HIP_MEMORY_SCOPE_AGENT);
    double g1 = __hip_atomic_load(&sl->s[1], __ATOMIC_RELAXED, __HIP_MEMORY_SCOPE_AGENT);
    double g2 = __hip_atomic_load(&sl->s[2], __ATOMIC_RELAXED, __HIP_MEMORY_SCOPE_AGENT);
    double g3 = __hip_atomic_load(&sl->s[3], __ATOMIC_RELAXED, __HIP_MEMORY_SCOPE_AGENT);
#pragma unroll
    for (int off = 32; off > 0; off >>= 1) {
      g0 += __shfl_down(g0, off, 64);
      g1 += __shfl_down(g1, off, 64);
      g2 += __shfl_down(g2, off, 64);
      g3 += __shfl_down(g3, off, 64);
    }
    if (lane == 0) { lg[wave][0] = g0; lg[wave][1] = g1; lg[wave][2] = g2; lg[wave][3] = g3; }
  }
  __syncthreads();
  if (threadIdx.x == 0) {
    const double t0 = lg[0][0] + lg[1][0] + lg[2][0] + lg[3][0];
    const double t1 = lg[0][1] + lg[1][1] + lg[2][1] + lg[3][1];
    const double t2 = lg[0][2] + lg[1][2] + lg[2][2] + lg[3][2];
    const double t3 = lg[0][3] + lg[1][3] + lg[2][3] + lg[3][3];
    const double m0 = t0 * dn, m1 = t1 * dn;
    const double v0 = fma(-m0, m0, t2 * dn);
    const double v1 = fma(-m1, m1, t3 * dn);
    const double rs0 = 1.0 / sqrt(v0 + 1e-5);
    const double rs1 = 1.0 / sqrt(v1 + 1e-5);
    const double A0 = (double)gmv0 * rs0, A1 = (double)gmv1 * rs1;
    const double C2 = 2.8853900817779268147;       // 2*log2(e)
    lc[0] = A0 * C2;
    lc[1] = A1 * C2;
    lc[2] = ((double)btv0 - m0 * A0) * C2;
    lc[3] = ((double)btv1 - m1 * A1) * C2;
  }
  __syncthreads();
  P0 = lc[0]; P1 = lc[1]; Q0 = lc[2]; Q1 = lc[3];
}

__global__ __launch_bounds__(NT, 4) void fraud_persist(
    const float4* __restrict__ x, const float* __restrict__ W,
    const float* __restrict__ b, const float* __restrict__ gm,
    const float* __restrict__ bt, const float* __restrict__ sc,
    const float* __restrict__ sh, const float* __restrict__ Wf,
    const float* __restrict__ bf, float2* __restrict__ out,
    Slot* __restrict__ slot, int N2, int L)
{
  const int tid = blockIdx.x * NT + threadIdx.x;
  float4 y[PRPT];                                  // activations live in registers all layers
  double s0 = 0, s1 = 0, s2 = 0, s3 = 0;

  // ---- pass 0: y0 = W0 x + b0 (+ stats of y0) ----
  {
    const double w00 = W[0], w01 = W[1], w10 = W[2], w11 = W[3];
    const double b0 = b[0], b1 = b[1];
#pragma unroll
    for (int r = 0; r < PRPT; ++r) {
      const int i = tid + r * TT;
      const float4 p = (i < N2) ? x[i] : make_float4(0.f, 0.f, 0.f, 0.f);
      const double a0 = fma((double)p.x, w00, fma((double)p.y, w01, b0));
      const double a1 = fma((double)p.x, w10, fma((double)p.y, w11, b1));
      const double a2 = fma((double)p.z, w00, fma((double)p.w, w01, b0));
      const double a3 = fma((double)p.z, w10, fma((double)p.w, w11, b1));
      y[r] = make_float4((float)a0, (float)a1, (float)a2, (float)a3);
      if (i < N2) {
        s0 += a0 + a2; s1 += a1 + a3;
        s2 = fma(a0, a0, fma(a2, a2, s2));
        s3 = fma(a1, a1, fma(a3, a3, s3));
      }
    }
  }
  const double dn = 0.5 / (double)N2;              // 1/N

  // software-pipelined params: loads for layer l issue BEFORE the barrier wait
  // that precedes their use, so they complete under the poll.
  float gmv0 = gm[0], gmv1 = gm[1], btv0 = bt[0], btv1 = bt[1];
  float sc0 = sc[0], sh0 = sh[0], sc1 = sc[1], sh1 = sh[1];

  double P0, P1, Q0, Q1;
  layer_sync(0, s0, s1, s2, s3, slot, gmv0, gmv1, btv0, btv1, dn, P0, P1, Q0, Q1);

  for (int l = 0; l < L; ++l) {
    const bool last = (l == L - 1);
    double w00, w01, w10 = 0, w11 = 0, b0, b1 = 0;
    if (!last) {
      w00 = W[4 * l + 4]; w01 = W[4 * l + 5]; w10 = W[4 * l + 6]; w11 = W[4 * l + 7];
      b0 = b[2 * l + 2]; b1 = b[2 * l + 3];
    } else { w00 = Wf[0]; w01 = Wf[1]; b0 = bf[0]; }
    const float csc0 = sc0, csh0 = sh0, csc1 = sc1, csh1 = sh1;

    s0 = 0; s1 = 0; s2 = 0; s3 = 0;
#pragma unroll
    for (int r = 0; r < PRPT; ++r) {
      const int i = tid + r * TT;
      const float z0 = actf(y[r].x, P0, Q0, csc0, csh0);
      const float z1 = actf(y[r].y, P1, Q1, csc1, csh1);
      const float z2 = actf(y[r].z, P0, Q0, csc0, csh0);
      const float z3 = actf(y[r].w, P1, Q1, csc1, csh1);
      if (!last) {
        const double a0 = fma((double)z0, w00, fma((double)z1, w01, b0));
        const double a1 = fma((double)z0, w10, fma((double)z1, w11, b1));
        const double a2 = fma((double)z2, w00, fma((double)z3, w01, b0));
        const double a3 = fma((double)z2, w10, fma((double)z3, w11, b1));
        y[r] = make_float4((float)a0, (float)a1, (float)a2, (float)a3);
        if (i < N2) {
          s0 += a0 + a2; s1 += a1 + a3;
          s2 = fma(a0, a0, fma(a2, a2, s2));
          s3 = fma(a1, a1, fma(a3, a3, s3));
        }
      } else if (i < N2) {
        const double u0 = fma((double)z0, w00, fma((double)z1, w01, b0));
        const double u1 = fma((double)z2, w00, fma((double)z3, w01, b0));
        out[i] = make_float2(sigm(u0), sigm(u1));
      }
    }
    if (!last) {
      // prefetch next layer's params NOW so the loads retire during the wait
      gmv0 = gm[2 * (l + 1)]; gmv1 = gm[2 * (l + 1) + 1];
      btv0 = bt[2 * (l + 1)]; btv1 = bt[2 * (l + 1) + 1];
      sc0 = sc[2 * (l + 1)]; sh0 = sh[2 * (l + 1)];
      sc1 = sc[2 * (l + 1) + 1]; sh1 = sh[2 * (l + 1) + 1];
      layer_sync(l + 1, s0, s1, s2, s3, slot, gmv0, gmv1, btv0, btv1, dn,
                 P0, P1, Q0, Q1);
    }
  }
}

extern "C" void kernel_launch(void* const* d_in, const int* in_sizes, int n_in,
                              void* d_out, int out_size, void* d_ws, size_t ws_size,
                              hipStream_t stream) {
  const float* x  = (const float*)d_in[0];
  const float* W  = (const float*)d_in[1];
  const float* b  = (const float*)d_in[2];
  const float* gm = (const float*)d_in[3];
  const float* bt = (const float*)d_in[4];
  const float* sc = (const float*)d_in[5];
  const float* sh = (const float*)d_in[6];
  const float* Wf = (const float*)d_in[7];
  const float* bf = (const float*)d_in[8];
  const int N  = in_sizes[0] / 2;
  const int L  = in_sizes[1] / 4;   // 48
  const int N2 = N / 2;             // float4 count (2 rows each)

  Slot* slot = (Slot*)d_ws;                        // 2 (parity) * NB slots * 128B = 64KB

  hipMemsetAsync(d_ws, 0, 2 * NB * sizeof(Slot), stream);  // zero flags each call

  fraud_persist<<<NB, NT, 0, stream>>>(
      (const float4*)x, W, b, gm, bt, sc, sh, Wf, bf,
      (float2*)d_out, slot, N2, L);
}